// Round 4
// baseline (311.371 us; speedup 1.0000x reference)
//
#include <hip/hip_runtime.h>
#include <hip/hip_bf16.h>

// GPConv1d as implicit-im2col GEMM: out[ok][b,w] = sum_{v,cj} kern[ok][(v,cj)] x[b][cj][w+v-2]
// M=512, N=32768, K=2560. K-loop: flat 40 steps s=(cjb,v); x window Bs staged once per cjb
// (serves all 5 v via row shift); kern tile (128 x 64, pad to 72) per (cjb,v), pre-tiled
// glds-ready, DOUBLE-BUFFERED so the 18.4 KB L2 reload overlaps compute. 32x32x16 MFMA.

#define C_    64
#define L_    4096
#define PAD_  2
#define CJ_   512
#define OKch  512

#define BM    128
#define BN    128
#define NCJB  8
#define NV    5
#define NSTEP 40                      // NCJB*NV
#define ASTR  72                      // row stride elems: 64 + 8 pad (144B: free phase pattern)
#define TILE_ELEMS (128 * ASTR)       // 9216 elems = 18432 B
#define NCHUNK (TILE_ELEMS / 8)       // 1152 x 16B glds chunks
#define WIN   132                     // Bs rows: w0-2 .. w0+129
#define NTASK (WIN * 8)               // 1056 transpose tasks per cjb

typedef __bf16 bf16x8 __attribute__((ext_vector_type(8)));
typedef float floatx16 __attribute__((ext_vector_type(16)));

__device__ __forceinline__ unsigned short f2bf(float f) {
    unsigned int u = __float_as_uint(f);
    u += 0x7FFFu + ((u >> 16) & 1u);
    return (unsigned short)(u >> 16);
}

__device__ __forceinline__ void glds16(const unsigned short* g, unsigned short* l) {
    __builtin_amdgcn_global_load_lds(
        (const __attribute__((address_space(1))) unsigned int*)(g),
        (__attribute__((address_space(3))) unsigned int*)(l),
        16, 0, 0);
}

// ---- kernel 1: build kern tiles. Thread computes 8 j-values for fixed (ok,v,c):
// kern(ok,(v,cj=c*8+j)) = sum_i G[i,j,kb] W[v,c,o,i]; one uint4 store.
// tile s-order: tile((y*8+cjb)*5+v)[m*72 + kk], y=ok>>7, m=ok&127, kk=(c&7)*8+j
__global__ __launch_bounds__(256) void build_kern(
    const float* __restrict__ W, const float* __restrict__ G,
    unsigned short* __restrict__ kernT)
{
    const int t  = blockIdx.x * 256 + threadIdx.x;  // 0..163839
    const int c  = t & 63;
    const int idx = t >> 6;                          // 0..2559
    const int v  = idx % 5;
    const int ok = idx / 5;
    const int o  = ok >> 3, kb = ok & 7;
    const int y  = ok >> 7, m  = ok & 127;
    const int cjb = c >> 3, kkb = (c & 7) << 3;

    const float* Wp = W + ((((v * 64 + c) * 64) + o) << 3);
    const float4 w0 = *(const float4*)Wp;
    const float4 w1 = *(const float4*)(Wp + 4);
    const float wv[8] = {w0.x, w0.y, w0.z, w0.w, w1.x, w1.y, w1.z, w1.w};

    unsigned int pk[4];
    #pragma unroll
    for (int j = 0; j < 8; j++) {
        const float* Gj = G + j * 8 + kb;            // G[i][j][kb], i stride 64
        float s = 0.f;
        #pragma unroll
        for (int i = 0; i < 8; i++) s += Gj[i * 64] * wv[i];
        const unsigned int h = f2bf(s);
        if (j & 1) pk[j >> 1] |= h << 16;
        else       pk[j >> 1]  = h;
    }
    unsigned short* dst =
        kernT + (size_t)(((y * NCJB + cjb) * NV + v)) * TILE_ELEMS + m * ASTR + kkb;
    uint4 u; u.x = pk[0]; u.y = pk[1]; u.z = pk[2]; u.w = pk[3];
    *reinterpret_cast<uint4*>(dst) = u;
}

// ---- kernel 2: MFMA GEMM, 128x128 C-tile, As double-buffered, 32x32x16 MFMA
__global__ __launch_bounds__(256, 2) void gpconv_mfma(
    const float* __restrict__ x, const unsigned short* __restrict__ kernT,
    const float* __restrict__ bias, float* __restrict__ out)
{
    __shared__ unsigned short Asd[2][TILE_ELEMS];  // 2 x 18432 B
    __shared__ unsigned short Bs[WIN * ASTR];      // 19008 B

    const int tid  = threadIdx.x;
    const int lane = tid & 63;
    const int wave = tid >> 6;
    const int l31  = lane & 31;
    const int lhi  = lane >> 5;                    // 0/1: k-half
    const int wm = (wave >> 1) << 6;               // 2x2 wave grid, 64x64 each
    const int wn = (wave & 1) << 6;

    // XCD-aware remap: 4 y-blocks sharing an x-window -> same XCD (ids differ by 8)
    const int bid = blockIdx.x;
    const int y   = (bid >> 3) & 3;
    const int xw  = ((bid >> 5) << 3) + (bid & 7);
    const int b   = xw >> 5;
    const int w0  = (xw & 31) * BN;
    const int mBase = y * BM;
    const float* xb = x + (size_t)b * (size_t)(CJ_ * L_);
    const unsigned short* ky = kernT + (size_t)(y * NCJB * NV) * TILE_ELEMS;

    floatx16 acc[2][2];
    #pragma unroll
    for (int i = 0; i < 2; i++)
        #pragma unroll
        for (int j = 0; j < 2; j++)
            #pragma unroll
            for (int e = 0; e < 16; e++) acc[i][j][e] = 0.f;

    unsigned int pk[5][4];   // x prefetch (packed bf16 pairs)

    // ---- helpers (lambdas keep the pipeline readable)
    auto stageA = [&](int s) {   // async glds tile s -> Asd[s&1]
        const unsigned short* tv = ky + (size_t)s * TILE_ELEMS;
        unsigned short* dst = Asd[s & 1];
        #pragma unroll
        for (int u = 0; u < 5; u++) {
            const int i = tid + (u << 8);
            if (i < NCHUNK) glds16(tv + (i << 3), dst + (i << 3));
        }
    };
    auto prefX = [&](int cjb) {  // global x -> pk regs (packed)
        const int cj0 = cjb << 6;
        #pragma unroll
        for (int u = 0; u < 5; u++) {
            const int t = tid + (u << 8);
            if (t < NTASK) {
                const int kgrp = t / WIN;
                const int nn   = t - kgrp * WIN;
                const int ws   = w0 - PAD_ + nn;
                const int cjw  = cj0 + (kgrp << 3);
                #pragma unroll
                for (int r = 0; r < 8; r++) {
                    float val = 0.f;
                    if ((unsigned)ws < (unsigned)L_)
                        val = xb[((size_t)(cjw + r) << 12) + (size_t)ws];
                    const unsigned int h = f2bf(val);
                    if (r & 1) pk[u][r >> 1] |= h << 16;
                    else       pk[u][r >> 1]  = h;
                }
            }
        }
    };
    auto writeB = [&]() {        // pk regs -> Bs
        #pragma unroll
        for (int u = 0; u < 5; u++) {
            const int t = tid + (u << 8);
            if (t < NTASK) {
                const int kgrp = t / WIN;
                const int nn   = t - kgrp * WIN;
                uint4 uu; uu.x = pk[u][0]; uu.y = pk[u][1]; uu.z = pk[u][2]; uu.w = pk[u][3];
                *reinterpret_cast<uint4*>(&Bs[nn * ASTR + (kgrp << 3)]) = uu;
            }
        }
    };

    // ---- prologue
    prefX(0);
    stageA(0);
    writeB();
    __syncthreads();     // drains glds(0), publishes Bs(0)
    stageA(1);

    // ---- flat pipeline over 40 (cjb,v) steps
    for (int s = 0; s < NSTEP; ++s) {
        const int cjb = s / 5;
        const int v   = s - cjb * 5;

        if (v == 2 && cjb < NCJB - 1) prefX(cjb + 1);   // in flight under compute

        // compute step s: K=64, 4 chunks of 16; uses Asd[s&1], Bs rows +v
        const unsigned short* As = Asd[s & 1];
        #pragma unroll
        for (int kc = 0; kc < 4; kc++) {
            const int ko = (kc << 4) + (lhi << 3);
            bf16x8 af[2], bf[2];
            #pragma unroll
            for (int mt = 0; mt < 2; mt++)
                af[mt] = *reinterpret_cast<const bf16x8*>(
                    &As[(wm + (mt << 5) + l31) * ASTR + ko]);
            #pragma unroll
            for (int nt = 0; nt < 2; nt++)
                bf[nt] = *reinterpret_cast<const bf16x8*>(
                    &Bs[(wn + (nt << 5) + l31 + v) * ASTR + ko]);
            #pragma unroll
            for (int mt = 0; mt < 2; mt++)
                #pragma unroll
                for (int nt = 0; nt < 2; nt++)
                    acc[mt][nt] = __builtin_amdgcn_mfma_f32_32x32x16_bf16(
                        af[mt], bf[nt], acc[mt][nt], 0, 0, 0);
        }

        __syncthreads();     // end-barrier: drains glds(s+1), retires reads of Asd[s&1], Bs
        if (s == NSTEP - 1) break;
        if (v == NV - 1) {   // next step starts cjb+1: publish its Bs (VALU-only gap)
            writeB();
            __syncthreads();
        }
        if (s + 2 < NSTEP) stageA(s + 2);   // overwrites Asd[s&1], reads retired above
    }

    // ---- epilogue: 32x32 C/D: col=lane&31, row=(e&3)+8*(e>>2)+4*(lane>>5)
    #pragma unroll
    for (int mt = 0; mt < 2; mt++) {
        #pragma unroll
        for (int e = 0; e < 16; e++) {
            const int row = (e & 3) + ((e >> 2) << 3) + (lhi << 2);
            const int okc = mBase + wm + (mt << 5) + row;
            const float bv = bias[okc];
            float* orow = out + ((size_t)b * OKch + (size_t)okc) * L_ + w0;
            #pragma unroll
            for (int nt = 0; nt < 2; nt++) {
                const int n = wn + (nt << 5) + l31;
                orow[n] = acc[mt][nt][e] + bv;
            }
        }
    }
}

extern "C" void kernel_launch(void* const* d_in, const int* in_sizes, int n_in,
                              void* d_out, int out_size, void* d_ws, size_t ws_size,
                              hipStream_t stream) {
    const float* x    = (const float*)d_in[0];  // (8,64,8,4096)
    const float* W    = (const float*)d_in[1];  // (5,64,64,8)
    const float* bias = (const float*)d_in[2];  // (1,64,8,1) -> [512]
    const float* G    = (const float*)d_in[3];  // (8,8,8)
    unsigned short* kernT = (unsigned short*)d_ws;  // 160 tiles x 18432 B = 2.95 MB
    float* out = (float*)d_out;

    build_kern<<<dim3(640), 256, 0, stream>>>(W, G, kernT);
    gpconv_mfma<<<dim3(1024), 256, 0, stream>>>(x, kernT, bias, out);
}

// Round 5
// 310.443 us; speedup vs baseline: 1.0030x; 1.0030x over previous
//
#include <hip/hip_runtime.h>
#include <hip/hip_bf16.h>

// GPConv1d as implicit-im2col GEMM: out[ok][b,w] = sum_{v,cj} kern[ok][(v,cj)] x[b][cj][w+v-2]
// M=512, N=32768, K=2560. Flat 40-step K-loop s=(cjb,v); x window Bs staged once per cjb
// (serves all 5 v via row shift); kern tile (128x64 pad 72) per (cjb,v), glds-ready,
// double-buffered. 32x32x16 MFMA (conflict-free frag pattern, verified R4).
// R5: per-block K-loop STAGGER (cjb0 = (bid>>3)&7) to kill the L2 kern-tile hotspot —
// without it, all resident blocks fetch the same 18.4KB tile each step in lockstep.

#define C_    64
#define L_    4096
#define PAD_  2
#define CJ_   512
#define OKch  512

#define BM    128
#define BN    128
#define NCJB  8
#define NV    5
#define NSTEP 40                      // NCJB*NV
#define ASTR  72                      // row stride elems: 64 + 8 pad
#define TILE_ELEMS (128 * ASTR)       // 9216 elems = 18432 B
#define NCHUNK (TILE_ELEMS / 8)       // 1152 x 16B glds chunks
#define WIN   132                     // Bs rows: w0-2 .. w0+129
#define NTASK (WIN * 8)               // 1056 transpose tasks per cjb

typedef __bf16 bf16x8 __attribute__((ext_vector_type(8)));
typedef float floatx16 __attribute__((ext_vector_type(16)));

__device__ __forceinline__ unsigned short f2bf(float f) {
    unsigned int u = __float_as_uint(f);
    u += 0x7FFFu + ((u >> 16) & 1u);
    return (unsigned short)(u >> 16);
}

__device__ __forceinline__ void glds16(const unsigned short* g, unsigned short* l) {
    __builtin_amdgcn_global_load_lds(
        (const __attribute__((address_space(1))) unsigned int*)(g),
        (__attribute__((address_space(3))) unsigned int*)(l),
        16, 0, 0);
}

// ---- kernel 1: build kern tiles (glds-ready, pad baked in).
// kern(ok,(v,cj=c*8+j)) = sum_i G[i,j,kb] W[v,c,o,i]
// tile ((y*8+cjb)*5+v)[m*72 + kk], y=ok>>7, m=ok&127, cjb=cj>>6... kk=(c&7)*8+j
__global__ __launch_bounds__(256) void build_kern(
    const float* __restrict__ W, const float* __restrict__ G,
    unsigned short* __restrict__ kernT)
{
    const int t  = blockIdx.x * 256 + threadIdx.x;  // 0..163839
    const int c  = t & 63;
    const int idx = t >> 6;                          // 0..2559
    const int v  = idx % 5;
    const int ok = idx / 5;
    const int o  = ok >> 3, kb = ok & 7;
    const int y  = ok >> 7, m  = ok & 127;
    const int cjb = c >> 3, kkb = (c & 7) << 3;

    const float* Wp = W + ((((v * 64 + c) * 64) + o) << 3);
    const float4 w0 = *(const float4*)Wp;
    const float4 w1 = *(const float4*)(Wp + 4);
    const float wv[8] = {w0.x, w0.y, w0.z, w0.w, w1.x, w1.y, w1.z, w1.w};

    unsigned int pk[4];
    #pragma unroll
    for (int j = 0; j < 8; j++) {
        const float* Gj = G + j * 8 + kb;            // G[i][j][kb], i stride 64
        float s = 0.f;
        #pragma unroll
        for (int i = 0; i < 8; i++) s += Gj[i * 64] * wv[i];
        const unsigned int h = f2bf(s);
        if (j & 1) pk[j >> 1] |= h << 16;
        else       pk[j >> 1]  = h;
    }
    unsigned short* dst =
        kernT + (size_t)(((y * NCJB + cjb) * NV + v)) * TILE_ELEMS + m * ASTR + kkb;
    uint4 u; u.x = pk[0]; u.y = pk[1]; u.z = pk[2]; u.w = pk[3];
    *reinterpret_cast<uint4*>(dst) = u;
}

// ---- kernel 2: MFMA GEMM, 128x128 C-tile, As double-buffered, staggered K-loop
__global__ __launch_bounds__(256, 2) void gpconv_mfma(
    const float* __restrict__ x, const unsigned short* __restrict__ kernT,
    const float* __restrict__ bias, float* __restrict__ out)
{
    __shared__ unsigned short Asd[2][TILE_ELEMS];  // 2 x 18432 B
    __shared__ unsigned short Bs[WIN * ASTR];      // 19008 B

    const int tid  = threadIdx.x;
    const int lane = tid & 63;
    const int wave = tid >> 6;
    const int l31  = lane & 31;
    const int lhi  = lane >> 5;
    const int wm = (wave >> 1) << 6;               // 2x2 wave grid, 64x64 each
    const int wn = (wave & 1) << 6;

    // XCD-aware remap: 4 y-blocks sharing an x-window -> same XCD (ids differ by 8)
    const int bid = blockIdx.x;
    const int y   = (bid >> 3) & 3;
    const int xw  = ((bid >> 5) << 3) + (bid & 7);
    const int b   = xw >> 5;
    const int w0  = (xw & 31) * BN;
    const int mBase = y * BM;
    const int cjb0 = (bid >> 3) & 7;               // K-loop stagger phase
    const float* xb = x + (size_t)b * (size_t)(CJ_ * L_);
    const unsigned short* ky = kernT + (size_t)(y * NCJB * NV) * TILE_ELEMS;

    floatx16 acc[2][2];
    #pragma unroll
    for (int i = 0; i < 2; i++)
        #pragma unroll
        for (int j = 0; j < 2; j++)
            #pragma unroll
            for (int e = 0; e < 16; e++) acc[i][j][e] = 0.f;

    unsigned int pk[5][4];   // x prefetch regs (packed bf16 pairs)

    // tile index for pipeline step s (staggered): cjb=(cjb0+s/5)&7, v=s%5
    auto tileOf = [&](int s) -> const unsigned short* {
        const int q = s / 5;
        const int v = s - q * 5;
        const int cjb = (cjb0 + q) & 7;
        return ky + (size_t)(cjb * NV + v) * TILE_ELEMS;
    };
    auto stageA = [&](int s) {   // async glds tile(s) -> Asd[s&1]
        const unsigned short* tv = tileOf(s);
        unsigned short* dst = Asd[s & 1];
        #pragma unroll
        for (int u = 0; u < 5; u++) {
            const int i = tid + (u << 8);
            if (i < NCHUNK) glds16(tv + (i << 3), dst + (i << 3));
        }
    };
    auto prefX = [&](int cjb) {  // global x -> pk regs (packed)
        const int cj0 = cjb << 6;
        #pragma unroll
        for (int u = 0; u < 5; u++) {
            const int t = tid + (u << 8);
            if (t < NTASK) {
                const int kgrp = t / WIN;
                const int nn   = t - kgrp * WIN;
                const int ws   = w0 - PAD_ + nn;
                const int cjw  = cj0 + (kgrp << 3);
                #pragma unroll
                for (int r = 0; r < 8; r++) {
                    float val = 0.f;
                    if ((unsigned)ws < (unsigned)L_)
                        val = xb[((size_t)(cjw + r) << 12) + (size_t)ws];
                    const unsigned int h = f2bf(val);
                    if (r & 1) pk[u][r >> 1] |= h << 16;
                    else       pk[u][r >> 1]  = h;
                }
            }
        }
    };
    auto writeB = [&]() {        // pk regs -> Bs
        #pragma unroll
        for (int u = 0; u < 5; u++) {
            const int t = tid + (u << 8);
            if (t < NTASK) {
                const int kgrp = t / WIN;
                const int nn   = t - kgrp * WIN;
                uint4 uu; uu.x = pk[u][0]; uu.y = pk[u][1]; uu.z = pk[u][2]; uu.w = pk[u][3];
                *reinterpret_cast<uint4*>(&Bs[nn * ASTR + (kgrp << 3)]) = uu;
            }
        }
    };

    // ---- prologue
    prefX(cjb0);
    stageA(0);
    writeB();
    __syncthreads();     // drains glds(0), publishes Bs(cjb0)
    stageA(1);

    // ---- staggered 40-step pipeline
    for (int s = 0; s < NSTEP; ++s) {
        const int q = s / 5;
        const int v = s - q * 5;

        if (v == 2 && q < NCJB - 1) prefX((cjb0 + q + 1) & 7);

        const unsigned short* As = Asd[s & 1];
        #pragma unroll
        for (int kc = 0; kc < 4; kc++) {
            const int ko = (kc << 4) + (lhi << 3);
            bf16x8 af[2], bf[2];
            #pragma unroll
            for (int mt = 0; mt < 2; mt++)
                af[mt] = *reinterpret_cast<const bf16x8*>(
                    &As[(wm + (mt << 5) + l31) * ASTR + ko]);
            #pragma unroll
            for (int nt = 0; nt < 2; nt++)
                bf[nt] = *reinterpret_cast<const bf16x8*>(
                    &Bs[(wn + (nt << 5) + l31 + v) * ASTR + ko]);
            #pragma unroll
            for (int mt = 0; mt < 2; mt++)
                #pragma unroll
                for (int nt = 0; nt < 2; nt++)
                    acc[mt][nt] = __builtin_amdgcn_mfma_f32_32x32x16_bf16(
                        af[mt], bf[nt], acc[mt][nt], 0, 0, 0);
        }

        __syncthreads();     // drains glds(s+1), retires reads of Asd[s&1] and Bs
        if (s == NSTEP - 1) break;
        if (v == NV - 1) {   // entering next cjb: publish its Bs
            writeB();
            __syncthreads();
        }
        if (s + 2 < NSTEP) stageA(s + 2);
    }

    // ---- epilogue: 32x32 C/D: col=lane&31, row=(e&3)+8*(e>>2)+4*(lane>>5)
    #pragma unroll
    for (int mt = 0; mt < 2; mt++) {
        #pragma unroll
        for (int e = 0; e < 16; e++) {
            const int row = (e & 3) + ((e >> 2) << 3) + (lhi << 2);
            const int okc = mBase + wm + (mt << 5) + row;
            const float bv = bias[okc];
            float* orow = out + ((size_t)b * OKch + (size_t)okc) * L_ + w0;
            #pragma unroll
            for (int nt = 0; nt < 2; nt++) {
                const int n = wn + (nt << 5) + l31;
                orow[n] = acc[mt][nt][e] + bv;
            }
        }
    }
}

extern "C" void kernel_launch(void* const* d_in, const int* in_sizes, int n_in,
                              void* d_out, int out_size, void* d_ws, size_t ws_size,
                              hipStream_t stream) {
    const float* x    = (const float*)d_in[0];  // (8,64,8,4096)
    const float* W    = (const float*)d_in[1];  // (5,64,64,8)
    const float* bias = (const float*)d_in[2];  // (1,64,8,1) -> [512]
    const float* G    = (const float*)d_in[3];  // (8,8,8)
    unsigned short* kernT = (unsigned short*)d_ws;  // 160 tiles x 18432 B = 2.95 MB
    float* out = (float*)d_out;

    build_kern<<<dim3(640), 256, 0, stream>>>(W, G, kernT);
    gpconv_mfma<<<dim3(1024), 256, 0, stream>>>(x, kernT, bias, out);
}

// Round 6
// 250.818 us; speedup vs baseline: 1.2414x; 1.2377x over previous
//
#include <hip/hip_runtime.h>
#include <hip/hip_bf16.h>

// GPConv1d as implicit-im2col GEMM: out[ok][b,w] = sum_{v,cj} kern[ok][(v,cj)] x[b][cj][w+v-2]
// M=512, N=32768, K=2560. 80-step K-loop s=(cjb2 0..15, v 0..4), K-chunk 32.
// Bs = x window staged once per cjb2 (serves all 5 v via row shift, n-row +v).
// As = kern tile (128x32, pad to 40) per step, glds-ready, DOUBLE-BUFFERED with
// small tiles so LDS stays 31KB -> 4 blocks/CU (R4/R5 lesson: 56KB -> 2 blocks/CU
// lost all cross-block latency hiding; occupancy beats intra-block pipelining).
// 32x32x16 MFMA, conflict-free frag pattern (verified R4: conflicts 1e7 -> 3e4).

#define C_    64
#define L_    4096
#define PAD_  2
#define CJ_   512
#define OKch  512

#define BM    128
#define BN    128
#define KK    32
#define NQ    16                      // 512/32 cj-blocks
#define NV    5
#define NSTEP 80                      // NQ*NV
#define BSTR  40                      // row stride elems: 32 + 8 pad
#define TILE2 (128 * BSTR)            // 5120 elems = 10240 B per kern tile
#define NCH2  (TILE2 / 8)             // 640 x 16B glds chunks
#define WIN   132                     // Bs rows: w0-2 .. w0+129
#define NTASK2 (WIN * 4)              // 528 transpose tasks per cjb2 (4 groups of 8 cj)

typedef __bf16 bf16x8 __attribute__((ext_vector_type(8)));
typedef float floatx16 __attribute__((ext_vector_type(16)));

__device__ __forceinline__ unsigned short f2bf(float f) {
    unsigned int u = __float_as_uint(f);
    u += 0x7FFFu + ((u >> 16) & 1u);
    return (unsigned short)(u >> 16);
}

__device__ __forceinline__ void glds16(const unsigned short* g, unsigned short* l) {
    __builtin_amdgcn_global_load_lds(
        (const __attribute__((address_space(1))) unsigned int*)(g),
        (__attribute__((address_space(3))) unsigned int*)(l),
        16, 0, 0);
}

// ---- kernel 1: build kern tiles (glds-ready, pad baked in, KK=32).
// kern(ok,(v,cj=c*8+j)) = sum_i G[i,j,kb] W[v,c,o,i]
// tile ((y*16+cjb2)*5+v)[m*40 + kk], y=ok>>7, m=ok&127, cjb2=c>>2, kk=(c&3)*8+j
__global__ __launch_bounds__(256) void build_kern(
    const float* __restrict__ W, const float* __restrict__ G,
    unsigned short* __restrict__ kernT)
{
    const int t  = blockIdx.x * 256 + threadIdx.x;  // 0..163839
    const int c  = t & 63;
    const int idx = t >> 6;                          // 0..2559
    const int v  = idx % 5;
    const int ok = idx / 5;
    const int o  = ok >> 3, kb = ok & 7;
    const int y  = ok >> 7, m  = ok & 127;
    const int cjb2 = c >> 2, kkb = (c & 3) << 3;

    const float* Wp = W + ((((v * 64 + c) * 64) + o) << 3);
    const float4 w0 = *(const float4*)Wp;
    const float4 w1 = *(const float4*)(Wp + 4);
    const float wv[8] = {w0.x, w0.y, w0.z, w0.w, w1.x, w1.y, w1.z, w1.w};

    unsigned int pk[4];
    #pragma unroll
    for (int j = 0; j < 8; j++) {
        const float* Gj = G + j * 8 + kb;            // G[i][j][kb], i stride 64
        float s = 0.f;
        #pragma unroll
        for (int i = 0; i < 8; i++) s += Gj[i * 64] * wv[i];
        const unsigned int h = f2bf(s);
        if (j & 1) pk[j >> 1] |= h << 16;
        else       pk[j >> 1]  = h;
    }
    unsigned short* dst =
        kernT + (size_t)((y * NQ + cjb2) * NV + v) * TILE2 + m * BSTR + kkb;
    uint4 u; u.x = pk[0]; u.y = pk[1]; u.z = pk[2]; u.w = pk[3];
    *reinterpret_cast<uint4*>(dst) = u;
}

// ---- kernel 2: MFMA GEMM, 128x128 C-tile, small dbuf As, 4 blocks/CU
__global__ __launch_bounds__(256, 4) void gpconv_mfma(
    const float* __restrict__ x, const unsigned short* __restrict__ kernT,
    const float* __restrict__ bias, float* __restrict__ out)
{
    __shared__ unsigned short Asd[2][TILE2];   // 2 x 10240 B
    __shared__ unsigned short Bs[WIN * BSTR];  // 10560 B

    const int tid  = threadIdx.x;
    const int lane = tid & 63;
    const int wave = tid >> 6;
    const int l31  = lane & 31;
    const int lhi  = lane >> 5;
    const int wm = (wave >> 1) << 6;           // 2x2 wave grid, 64x64 each
    const int wn = (wave & 1) << 6;

    // 4 y-blocks sharing an x-window -> adjacent-by-8 ids -> same XCD slot
    const int bid = blockIdx.x;
    const int y   = (bid >> 3) & 3;
    const int xw  = ((bid >> 5) << 3) + (bid & 7);
    const int b   = xw >> 5;
    const int w0  = (xw & 31) * BN;
    const int mBase = y * BM;
    const float* xb = x + (size_t)b * (size_t)(CJ_ * L_);
    const unsigned short* ky = kernT + (size_t)(y * NQ * NV) * TILE2;

    floatx16 acc[2][2];
    #pragma unroll
    for (int i = 0; i < 2; i++)
        #pragma unroll
        for (int j = 0; j < 2; j++)
            #pragma unroll
            for (int e = 0; e < 16; e++) acc[i][j][e] = 0.f;

    unsigned int pk[3][4];   // x prefetch regs (packed bf16 pairs)

    auto stageA = [&](int s) {   // async glds tile(s) -> Asd[s&1]; tiles linear in s
        const unsigned short* tv = ky + (size_t)s * TILE2;
        unsigned short* dst = Asd[s & 1];
        #pragma unroll
        for (int u = 0; u < 3; u++) {
            const int i = tid + (u << 8);
            if (i < NCH2) glds16(tv + (i << 3), dst + (i << 3));
        }
    };
    auto prefX = [&](int q) {    // global x -> pk regs (packed)
        const int cj0 = q << 5;
        #pragma unroll
        for (int u = 0; u < 3; u++) {
            const int t = tid + (u << 8);
            if (t < NTASK2) {
                const int kgrp = t / WIN;          // 0..3
                const int nn   = t - kgrp * WIN;   // 0..131
                const int ws   = w0 - PAD_ + nn;
                const int cjw  = cj0 + (kgrp << 3);
                #pragma unroll
                for (int r = 0; r < 8; r++) {
                    float val = 0.f;
                    if ((unsigned)ws < (unsigned)L_)
                        val = xb[((size_t)(cjw + r) << 12) + (size_t)ws];
                    const unsigned int h = f2bf(val);
                    if (r & 1) pk[u][r >> 1] |= h << 16;
                    else       pk[u][r >> 1]  = h;
                }
            }
        }
    };
    auto writeB = [&]() {        // pk regs -> Bs
        #pragma unroll
        for (int u = 0; u < 3; u++) {
            const int t = tid + (u << 8);
            if (t < NTASK2) {
                const int kgrp = t / WIN;
                const int nn   = t - kgrp * WIN;
                uint4 uu; uu.x = pk[u][0]; uu.y = pk[u][1]; uu.z = pk[u][2]; uu.w = pk[u][3];
                *reinterpret_cast<uint4*>(&Bs[nn * BSTR + (kgrp << 3)]) = uu;
            }
        }
    };

    // ---- prologue
    prefX(0);
    stageA(0);
    writeB();
    __syncthreads();     // drains glds(0), publishes Bs(q=0)
    stageA(1);

    // ---- 80-step pipeline, one barrier per step
    for (int s = 0; s < NSTEP; ++s) {
        const int q = s / 5;
        const int v = s - q * 5;

        if (v == 2 && q < NQ - 1) prefX(q + 1);   // in flight until the step barrier

        // compute step s: K=32 (2 chunks of 16); uses Asd[s&1], Bs rows +v
        const unsigned short* As = Asd[s & 1];
        #pragma unroll
        for (int kc = 0; kc < 2; kc++) {
            const int ko = (kc << 4) + (lhi << 3);
            bf16x8 af[2], bf[2];
            #pragma unroll
            for (int mt = 0; mt < 2; mt++)
                af[mt] = *reinterpret_cast<const bf16x8*>(
                    &As[(wm + (mt << 5) + l31) * BSTR + ko]);
            #pragma unroll
            for (int nt = 0; nt < 2; nt++)
                bf[nt] = *reinterpret_cast<const bf16x8*>(
                    &Bs[(wn + (nt << 5) + l31 + v) * BSTR + ko]);
            #pragma unroll
            for (int mt = 0; mt < 2; mt++)
                #pragma unroll
                for (int nt = 0; nt < 2; nt++)
                    acc[mt][nt] = __builtin_amdgcn_mfma_f32_32x32x16_bf16(
                        af[mt], bf[nt], acc[mt][nt], 0, 0, 0);
        }

        __syncthreads();   // drains glds(s+1) (+prefX); retires frag/Bs reads of step s
        if (s == NSTEP - 1) break;
        if (v == NV - 1) { // entering q+1: publish its Bs (reads retired above)
            writeB();
            __syncthreads();
        }
        if (s + 2 < NSTEP) stageA(s + 2);  // Asd[s&1] free: its reads retired above
    }

    // ---- epilogue: 32x32 C/D: col=lane&31, row=(e&3)+8*(e>>2)+4*(lane>>5)
    #pragma unroll
    for (int mt = 0; mt < 2; mt++) {
        #pragma unroll
        for (int e = 0; e < 16; e++) {
            const int row = (e & 3) + ((e >> 2) << 3) + (lhi << 2);
            const int okc = mBase + wm + (mt << 5) + row;
            const float bv = bias[okc];
            float* orow = out + ((size_t)b * OKch + (size_t)okc) * L_ + w0;
            #pragma unroll
            for (int nt = 0; nt < 2; nt++) {
                const int n = wn + (nt << 5) + l31;
                orow[n] = acc[mt][nt][e] + bv;
            }
        }
    }
}

extern "C" void kernel_launch(void* const* d_in, const int* in_sizes, int n_in,
                              void* d_out, int out_size, void* d_ws, size_t ws_size,
                              hipStream_t stream) {
    const float* x    = (const float*)d_in[0];  // (8,64,8,4096)
    const float* W    = (const float*)d_in[1];  // (5,64,64,8)
    const float* bias = (const float*)d_in[2];  // (1,64,8,1) -> [512]
    const float* G    = (const float*)d_in[3];  // (8,8,8)
    unsigned short* kernT = (unsigned short*)d_ws;  // 320 tiles x 10240 B = 3.28 MB
    float* out = (float*)d_out;

    build_kern<<<dim3(640), 256, 0, stream>>>(W, G, kernT);
    gpconv_mfma<<<dim3(1024), 256, 0, stream>>>(x, kernT, bias, out);
}